// Round 17
// baseline (123.265 us; speedup 1.0000x reference)
//
#include <hip/hip_runtime.h>

// Problem constants (match reference)
#define BATCHN 32
#define NCELL  4096
#define BN     (BATCHN * NCELL)

// Round 17: hand-emitted VOP3P packed-f32 eval (inline asm).
// Theory: the ~8cyc-per-counted-v2f-op constant (6 rounds confirmed) is
// the compiler SCALARIZING ext_vector f32 math (LLVM rarely forms
// v_pk_*_f32 from <2 x float>; v_pk_max_f32 doesn't exist). Real cost =
// ~90 scalar instr/step x ~4cyc. Fix: eval2 (20 of 45 ops, pure
// pair->pair dataflow) via 10 asm VOP3P ops (v_pk_mul_f32/v_pk_fma_f32),
// coefficients hoisted into loop-invariant VGPR pairs. fma-for-fma,
// same Horner order -> bit-identical (absmax expected 0.00390625).
// Geometry unchanged: CPL=4, OWN=128, HALO=64, KSTEP=60, D=10, 1024 waves.
constexpr int OWN    = 128;
constexpr int HALO   = 64;
constexpr int CPL    = 4;                  // cells per lane
constexpr int KSTEP  = 60;                 // steps per launch (< HALO)
constexpr int CHUNKS = NCELL / OWN;        // 32

typedef float v2f __attribute__((ext_vector_type(2)));

// --- VOP3P packed f32 (CDNA dual-issue path; elementwise on reg pairs) ---
__device__ __forceinline__ v2f pk_mul(v2f a, v2f b) {
    v2f d;
    asm("v_pk_mul_f32 %0, %1, %2" : "=v"(d) : "v"(a), "v"(b));
    return d;
}
__device__ __forceinline__ v2f pk_fma(v2f a, v2f b, v2f c) {
    v2f d;
    asm("v_pk_fma_f32 %0, %1, %2, %3" : "=v"(d) : "v"(a), "v"(b), "v"(c));
    return d;
}

// Horner coefficients as loop-invariant VGPR pairs (VOP3P can't take
// literals; SGPR broadcast would need 64b pairs -- VGPR consts simplest).
struct PkC {
    v2f A, B, C, D, E75, F, G, H;
};

// hf = 0.5*f_real(u), hd = 0.5*f_real'(u) (signed; |.| applied at max).
// Same Horner order as R16 (verified at u=1: f=1,f'=0; u=0.5: f=0.710286,
// f'=1.085938):
//  hf = u*(0.75 + u*(0.3125 + u*(-13/12 + u*(0.625 - (5/48)u^2))))
//  hd = 0.75 + u*(0.625 + u*(-3.25 + u*(2.5 - 0.625u^2)))
__device__ __forceinline__ void eval2(v2f u, v2f& hf, v2f& hd, const PkC& k) {
    v2f u2 = pk_mul(u, u);
    v2f s0 = pk_fma(u2, k.A, k.B);    // -5/48 u^2 + 0.625
    v2f s1 = pk_fma(u, s0, k.C);      // ... -13/12
    v2f s2 = pk_fma(u, s1, k.D);      // ... +0.3125
    v2f s3 = pk_fma(u, s2, k.E75);    // ... +0.75
    hf = pk_mul(u, s3);
    v2f t0 = pk_fma(u2, k.F, k.G);    // -0.625 u^2 + 2.5
    v2f t1 = pk_fma(u, t0, k.H);      // ... -3.25
    v2f t2 = pk_fma(u, t1, k.B);      // ... +0.625 (reuse B)
    hd = pk_fma(u, t2, k.E75);        // ... +0.75
}

__device__ __forceinline__ v2f vmaxabs2(v2f a, v2f b) {
    v2f r;
    r.x = fmaxf(fabsf(a.x), fabsf(b.x));   // v_max_f32 with |src| modifiers
    r.y = fmaxf(fabsf(a.y), fabsf(b.y));
    return r;
}

// lane i <- lane i-1 (edge lane keeps self): DPP WAVE_SHR:1 = 0x138
__device__ __forceinline__ float dpp_left(float v) {
    int i = __float_as_int(v);
    return __int_as_float(
        __builtin_amdgcn_update_dpp(i, i, 0x138, 0xF, 0xF, false));
}
// lane i <- lane i+1 (edge lane keeps self): DPP WAVE_SHL:1 = 0x130
__device__ __forceinline__ float dpp_right(float v) {
    int i = __float_as_int(v);
    return __int_as_float(
        __builtin_amdgcn_update_dpp(i, i, 0x130, 0xF, 0xF, false));
}

// One LF step on 4 cells/lane in even/odd layout E={u0,u2}, O={u1,u3}.
__device__ __forceinline__ void lf_step(v2f& E, v2f& O, float b[CPL],
                                        bool bcL, bool bcR, float dtdx,
                                        const PkC& k) {
    v2f hfE, hdE, hfO, hdO;
    eval2(E, hfE, hdE, k);
    eval2(O, hfO, hdO, k);

    // exchange: only right neighbor's c0 family (3 DPP)
    float ur  = dpp_right(E.x);
    float hfr = dpp_right(hfE.x);
    float hdr = dpp_right(hdE.x);

    // interfaces i1(c0,c1), i3(c2,c3): fully packed
    v2f F13 = (hfE + hfO) - vmaxabs2(hdE, hdO) * (O - E);
    // interfaces i2(c1,c2), i4(c3, right c0): R-halves {E.y, r}
    v2f Rhf, Ru, Rhd;
    Rhf.x = hfE.y; Rhf.y = hfr;
    Ru.x  = E.y;   Ru.y  = ur;
    Rhd.x = hdE.y; Rhd.y = hdr;
    v2f F24 = (hfO + Rhf) - vmaxabs2(hdO, Rhd) * (Ru - O);

    // left-edge flux = left neighbor's right-edge flux (bit-identical for
    // interior lanes; lane-0 halo garbage firewalled away from owned cells)
    float i0 = dpp_left(F24.y);

    v2f G;
    G.x = i0; G.y = F24.x;
    v2f nE = E - dtdx * (F13 - G);
    v2f nO = O - dtdx * (F24 - F13);

    // outflow BCs: u[0]=u[1] (cell0 <- cell1), u[N-1]=u[N-2] (cell3 <- cell2)
    if (bcL) nE.x = nO.x;
    if (bcR) nO.y = nE.y;

    b[0] = nE.x; b[1] = nO.x; b[2] = nE.y; b[3] = nO.y;
    E = nE;
    O = nO;
}

__global__ __launch_bounds__(64) void lf_wave(const float* __restrict__ in_state,
                                              float* __restrict__ out,
                                              int s0, int nsteps) {
    const int lane  = threadIdx.x;          // one wave per block
    const int wid   = blockIdx.x;
    const int chunk = wid & (CHUNKS - 1);
    const int row   = wid >> 5;             // CHUNKS == 32
    const int gbase = chunk * OWN - HALO;
    const int c0    = lane * CPL;

    const float dtdx = (float)(0.0009 / (10.0 / 4096.0));

    // loop-invariant packed coefficient registers
    PkC k;
    k.A   = (v2f){-0.10416666666666667f, -0.10416666666666667f};
    k.B   = (v2f){0.625f, 0.625f};
    k.C   = (v2f){-1.0833333333333333f, -1.0833333333333333f};
    k.D   = (v2f){0.3125f, 0.3125f};
    k.E75 = (v2f){0.75f, 0.75f};
    k.F   = (v2f){-0.625f, -0.625f};
    k.G   = (v2f){2.5f, 2.5f};
    k.H   = (v2f){-3.25f, -3.25f};

    float uin[CPL];
    {
        const float* ip = in_state + (size_t)row * NCELL;
        #pragma unroll
        for (int j = 0; j < CPL; ++j) {
            int g = gbase + c0 + j;
            g = min(max(g, 0), NCELL - 1);
            uin[j] = ip[g];
        }
    }
    v2f E, O;
    E.x = uin[0]; E.y = uin[2];
    O.x = uin[1]; O.y = uin[3];

    // owned cells [64,192) -> lanes 16..47 (all 4 cells contiguous)
    const bool owned = (lane >= 16) && (lane < 48);
    const bool bcL = (chunk == 0) && (lane == 16);            // global cell 0
    const bool bcR = (chunk == CHUNKS - 1) && (lane == 47);   // global cell N-1

    float* op = out + (size_t)(s0 + 1) * BN + (size_t)row * NCELL + (gbase + c0);

    // dispatch 0: write plane 0 (= init), replacing the d2d memcpy
    if (s0 == 0 && owned) {
        *(float4*)(op - BN) = make_float4(uin[0], uin[1], uin[2], uin[3]);
    }

    int t = 0;
    // groups of 4 steps, stores batched per group in one exec region
    for (; t + 4 <= nsteps; t += 4) {
        float b0[CPL], b1[CPL], b2[CPL], b3[CPL];
        lf_step(E, O, b0, bcL, bcR, dtdx, k);
        lf_step(E, O, b1, bcL, bcR, dtdx, k);
        lf_step(E, O, b2, bcL, bcR, dtdx, k);
        lf_step(E, O, b3, bcL, bcR, dtdx, k);
        if (owned) {
            *(float4*)(op)            = make_float4(b0[0], b0[1], b0[2], b0[3]);
            *(float4*)(op + BN)       = make_float4(b1[0], b1[1], b1[2], b1[3]);
            *(float4*)(op + 2 * BN)   = make_float4(b2[0], b2[1], b2[2], b2[3]);
            *(float4*)(op + 3 * BN)   = make_float4(b3[0], b3[1], b3[2], b3[3]);
        }
        op += 4 * BN;
    }
    // tail (not hit for nsteps=60, kept for robustness)
    for (; t < nsteps; ++t) {
        float b[CPL];
        lf_step(E, O, b, bcL, bcR, dtdx, k);
        if (owned) *(float4*)op = make_float4(b[0], b[1], b[2], b[3]);
        op += BN;
    }
}

extern "C" void kernel_launch(void* const* d_in, const int* in_sizes, int n_in,
                              void* d_out, int out_size, void* d_ws, size_t ws_size,
                              hipStream_t stream) {
    const float* init = (const float*)d_in[0];
    float* out = (float*)d_out;

    const int total = out_size / BN - 1;

    const int nblocks = CHUNKS * BATCHN;    // 1024 waves, 1/SIMD chip-wide
    for (int s = 0; s < total; s += KSTEP) {
        int ns = (total - s) < KSTEP ? (total - s) : KSTEP;
        const float* src = (s == 0) ? init : out + (size_t)s * BN;
        lf_wave<<<nblocks, 64, 0, stream>>>(src, out, s, ns);
    }
}